// Round 10
// baseline (324.361 us; speedup 1.0000x reference)
//
#include <hip/hip_runtime.h>
#include <hip/hip_bf16.h>
#include <math.h>

#define T_TOK 2048
#define HDIM 1024
#define IDIM 4096
#define NEXP 8
#define RROWS 3200    // 3072 usable routed rows + 128 guaranteed-zero dummy rows
#define AROWS 5248    // 2048 shared + RROWS
#define ZROW  5120    // absolute row of the 128 dummy zero rows (= T_TOK + 3072)
#define NP2   24      // pair-tile entries: 8 shared + <=15 routed + pad
#define BK 64

typedef unsigned int uint;
typedef unsigned short ushort;
typedef __attribute__((ext_vector_type(4))) float f32x4;
typedef __attribute__((ext_vector_type(8))) short bf16x8;

__device__ __forceinline__ ushort f2bf(float f) {
  union { float f; uint u; } c; c.f = f;
  uint u = c.u;
  return (ushort)((u + 0x7FFFu + ((u >> 16) & 1u)) >> 16);  // RNE
}
__device__ __forceinline__ uint cvtpk(float a, float b) {
  uint r;
  asm("v_cvt_pk_bf16_f32 %0, %1, %2" : "=v"(r) : "v"(a), "v"(b));
  return r;
}
__device__ __forceinline__ uint4 cvt8(const float4 a, const float4 b) {
  uint4 r;
  r.x = cvtpk(a.x, a.y); r.y = cvtpk(a.z, a.w);
  r.z = cvtpk(b.x, b.y); r.w = cvtpk(b.z, b.w);
  return r;
}
// async global->LDS, 16B per lane; LDS dest is wave-uniform base + lane*16
__device__ __forceinline__ void gld16(ushort* lds, const ushort* g) {
  __builtin_amdgcn_global_load_lds(
      (const __attribute__((address_space(1))) uint*)g,
      (__attribute__((address_space(3))) uint*)lds, 16, 0, 0);
}

// counted-vmcnt barrier: keep newest N vmem ops in flight across the barrier
#define SYNCV(N) { \
  __builtin_amdgcn_sched_barrier(0); \
  asm volatile("s_waitcnt vmcnt(" #N ") lgkmcnt(0)" ::: "memory"); \
  __builtin_amdgcn_s_barrier(); \
  __builtin_amdgcn_sched_barrier(0); }

// ---------------- router: logits, top-1, sigmoid, scores out, hs->bf16 ----
__global__ __launch_bounds__(256) void router_kernel(
    const float* __restrict__ hs, const float* __restrict__ rw,
    ushort* __restrict__ Xall, float* __restrict__ scores_out,
    int* __restrict__ eidx, float* __restrict__ sval)
{
  const int wave = threadIdx.x >> 6;
  const int lane = threadIdx.x & 63;
  const int t = blockIdx.x * 4 + wave;
  const float* row = hs + (size_t)t * HDIM;
  float v[16];
  #pragma unroll
  for (int i = 0; i < 16; ++i) {
    v[i] = row[lane + 64 * i];
    Xall[(size_t)t * HDIM + lane + 64 * i] = f2bf(v[i]);
  }
  float logit[8];
  #pragma unroll
  for (int e = 0; e < 8; ++e) {
    const float* wr = rw + e * HDIM;
    float s = 0.f;
    #pragma unroll
    for (int i = 0; i < 16; ++i) s += v[i] * wr[lane + 64 * i];
    #pragma unroll
    for (int off = 32; off; off >>= 1) s += __shfl_xor(s, off, 64);
    logit[e] = s;
  }
  if (lane == 0) {
    int be = 0; float bv = logit[0];
    #pragma unroll
    for (int e = 1; e < 8; ++e) if (logit[e] > bv) { bv = logit[e]; be = e; }
    float sc = 1.f / (1.f + expf(-bv));
    eidx[t] = be; sval[t] = sc;
    #pragma unroll
    for (int e = 0; e < 8; ++e) scores_out[(size_t)e * T_TOK + t] = (e == be) ? sc : 0.f;
  }
}

// ---------------- plan: counts, 128-aligned segments, slots, PAIR tiles ---
// pairs[i] = {rowA, rowB, expert(-1=shared), valid}
__global__ __launch_bounds__(256) void plan_kernel(
    const int* __restrict__ eidx, int* __restrict__ row2tok, int4* __restrict__ pairs)
{
  __shared__ int cnt[8];
  __shared__ int slot[8];
  const int tid = threadIdx.x;
  if (tid < 8) cnt[tid] = 0;
  __syncthreads();
  for (int t = tid; t < T_TOK; t += 256) atomicAdd(&cnt[eidx[t]], 1);
  __syncthreads();
  if (tid == 0) {
    int np = 0;
    for (int i = 0; i < 8; ++i) pairs[np++] = make_int4(i * 256, i * 256 + 128, -1, 1);
    int o = 0;
    for (int e = 0; e < 8; ++e) {
      slot[e] = o;
      int cap = (cnt[e] + 127) & ~127;
      int nt = cap / 128;
      for (int j = 0; j < nt; j += 2) {
        int ra = T_TOK + o + j * 128;
        int rb = (j + 1 < nt) ? ra + 128 : ZROW;
        pairs[np++] = make_int4(ra, rb, e, 1);
      }
      o += cap;
    }
    for (; np < NP2; ++np) pairs[np] = make_int4(ZROW, ZROW, 0, 0);
  }
  for (int r = tid; r < RROWS; r += 256) row2tok[r] = -1;
  __syncthreads();
  for (int t = tid; t < T_TOK; t += 256) {
    int e = eidx[t];
    int s = atomicAdd(&slot[e], 1);
    row2tok[s] = t;
  }
}

// ---------------- gather: X'[slot] = score * hs[tok] (bf16), 0 for pad ----
__global__ __launch_bounds__(256) void gather_kernel(
    const float* __restrict__ hs, const int* __restrict__ row2tok,
    const float* __restrict__ sval, ushort* __restrict__ Xall)
{
  const int r = blockIdx.x;
  const int t = row2tok[r];
  const int c0 = threadIdx.x * 4;
  ushort4 o;
  if (t >= 0) {
    const float sc = sval[t];
    float4 v = *(const float4*)(hs + (size_t)t * HDIM + c0);
    o.x = f2bf(sc * v.x); o.y = f2bf(sc * v.y); o.z = f2bf(sc * v.z); o.w = f2bf(sc * v.w);
  } else { o.x = o.y = o.z = o.w = 0; }
  *(ushort4*)(Xall + (size_t)(T_TOK + r) * HDIM + c0) = o;
}

// ---------------- GEMM1: act = silu(X*Wg^T) * (X*Wu^T), bf16 out ---------
// 256x128 tile, 512 thr / 8 waves, wave 64x64 dual-acc, BK=64.
// A: 2-buf global_load_lds (4 DMA/thread/step). B: fp32 8xfloat4/thread,
// post-MFMA cvt+ds_write. SYNCV(8) leaves next-next-step's B loads in flight.
// LDS slot layout: (rowgrp)[kc 0..7][row%16] 16B slots.
#define LOADB1(k0) { \
  const float4* gp_ = (const float4*)(gptr + (k0)); \
  gr[0]=gp_[0]; gr[1]=gp_[1]; gr[2]=gp_[2]; gr[3]=gp_[3]; \
  const float4* up_ = (const float4*)(uptr + (k0)); \
  ur[0]=up_[0]; ur[1]=up_[1]; ur[2]=up_[2]; ur[3]=up_[3]; }

#define WRITEB1(BG, BU) { \
  *(uint4*)((BG) + woff0) = cvt8(gr[0], gr[1]); \
  *(uint4*)((BG) + woff0 + 128) = cvt8(gr[2], gr[3]); \
  *(uint4*)((BU) + woff0) = cvt8(ur[0], ur[1]); \
  *(uint4*)((BU) + woff0 + 128) = cvt8(ur[2], ur[3]); }

#define STAGEA(DST, SRC, LD, k0) { \
  gld16((DST) + alds0, (SRC) + (k0)); \
  gld16((DST) + alds0 + 512, (SRC) + (size_t)(LD) + 32 + (k0)); \
  gld16((DST) + alds0 + 1024, (SRC) + (size_t)16 * (LD) + (k0)); \
  gld16((DST) + alds0 + 1536, (SRC) + (size_t)17 * (LD) + 32 - (LD) + (size_t)(LD) + (k0)); }
// note: alds0 = w*2048 + lane*8; the 4 DMAs cover (rg=w*2,kch=0),(rg=w*2,kch=1),
// (rg=w*2+1,kch=0),(rg=w*2+1,kch=1); sources offset by kch*32 elems and +16 rows.

#define MFMAH1 \
  _Pragma("unroll") \
  for (int m = 0; m < 4; ++m) { \
    _Pragma("unroll") \
    for (int n = 0; n < 4; ++n) { \
      accg[m][n] = __builtin_amdgcn_mfma_f32_16x16x32_bf16(af[m], gf[n], accg[m][n], 0, 0, 0); \
      accu[m][n] = __builtin_amdgcn_mfma_f32_16x16x32_bf16(af[m], uf[n], accu[m][n], 0, 0, 0); } }

__global__ __launch_bounds__(512, 1) void gemm1_kernel(
    const ushort* __restrict__ Xall,
    const float* __restrict__ w_gate, const float* __restrict__ w_up,
    const float* __restrict__ ws_gate, const float* __restrict__ ws_up,
    const int4* __restrict__ pairs, ushort* __restrict__ actall)
{
  __shared__ __align__(16) ushort As[2][16384];   // 256x64 bf16 each
  __shared__ __align__(16) ushort Bg_[2][8192];   // 128x64 bf16 each
  __shared__ __align__(16) ushort Bu_[2][8192];

  // XCD panel-serialized order: XCD j (= b%8) sweeps all 24 pairs of panel j.
  const int b0 = blockIdx.x;
  const int j = b0 & 7, s0 = b0 >> 3;
  const int panel = j + 8 * (s0 / NP2);
  const int4 td = pairs[s0 % NP2];
  if (td.w == 0) return;
  const int r0a = td.x, r0b = td.y, e = td.z;
  const float* __restrict__ gbase = (e < 0) ? ws_gate : w_gate + (size_t)e * IDIM * HDIM;
  const float* __restrict__ ubase = (e < 0) ? ws_up   : w_up   + (size_t)e * IDIM * HDIM;
  const int col0 = panel * 128;

  const int tid = threadIdx.x;
  const int lane = tid & 63;
  const int w = tid >> 6;            // 8 waves
  const int wm = w >> 1, wn = w & 1; // wave tile: rows wm*64, cols wn*64

  // B staging: thread -> row tid>>2 (128 rows), 16 consecutive floats at (tid&3)*16
  const int brow = tid >> 2, bc = tid & 3;
  const float* gptr = gbase + (size_t)(col0 + brow) * HDIM + bc * 16;
  const float* uptr = ubase + (size_t)(col0 + brow) * HDIM + bc * 16;
  const int woff0 = ((brow >> 4) << 10) + (bc * 2) * 128 + ((brow & 15) << 3);

  // A staging: wave w covers rows [w*32, w*32+32); lane -> row (lane&15), kc (lane>>4)
  const int rowb = (w < 4) ? (r0a + w * 32) : (r0b + (w - 4) * 32);
  const ushort* asrc = Xall + (size_t)(rowb + (lane & 15)) * HDIM + (lane >> 4) * 8;
  const int alds0 = w * 2048 + lane * 8;

  ushort* a0 = &As[0][0];
  ushort* a1 = &As[1][0];
  ushort* bg0 = &Bg_[0][0]; ushort* bg1 = &Bg_[1][0];
  ushort* bu0 = &Bu_[0][0]; ushort* bu1 = &Bu_[1][0];

  float4 gr[4], ur[4];
  const int loff = ((lane >> 4) << 7) + ((lane & 15) << 3);
  f32x4 accg[4][4] = {};
  f32x4 accu[4][4] = {};

  // A DMA helper offsets captured via macro (uses asrc, HDIM, alds0)
  #define STAGEA1(DST, k0) { \
    gld16((DST) + alds0,        asrc + (k0)); \
    gld16((DST) + alds0 + 512,  asrc + 32 + (k0)); \
    gld16((DST) + alds0 + 1024, asrc + (size_t)16 * HDIM + (k0)); \
    gld16((DST) + alds0 + 1536, asrc + (size_t)16 * HDIM + 32 + (k0)); }

  // prologue: B(0) regs -> buf0; A(0) -> a0; B(1) regs held
  LOADB1(0);
  STAGEA1(a0, 0);
  WRITEB1(bg0, bu0);      // auto-waits B(0) loads (A(0) issued after -> stays)
  LOADB1(BK);
  SYNCV(8);               // drain A(0); leave B(1)'s 8 loads in flight

  const int NS = HDIM / BK;  // 16
  for (int s = 0; s < NS - 2; ++s) {
    STAGEA1(a1, (s + 1) * BK);
    #pragma unroll
    for (int h = 0; h < 2; ++h) {
      bf16x8 af[4], gf[4], uf[4];
      const int hoff = h * 512 + loff;
      #pragma unroll
      for (int m = 0; m < 4; ++m) af[m] = *(const bf16x8*)(a0 + (wm * 4 + m) * 1024 + hoff);
      #pragma unroll
      for (int n = 0; n < 4; ++n) {
        gf[n] = *(const bf16x8*)(bg0 + (wn * 4 + n) * 1024 + hoff);
        uf[n] = *(const bf16x8*)(bu0 + (wn * 4 + n) * 1024 + hoff);
      }
      MFMAH1;
      __builtin_amdgcn_sched_barrier(0);
    }
    WRITEB1(bg1, bu1);     // waits B(s+1) regs
    LOADB1((s + 2) * BK);  // B(s+2)
    SYNCV(8);              // leave B(s+2); drain A(s+1)
    { ushort* t_;
      t_ = a0; a0 = a1; a1 = t_;
      t_ = bg0; bg0 = bg1; bg1 = t_;
      t_ = bu0; bu0 = bu1; bu1 = t_; }
  }
  {   // step NS-2: stage A(NS-1), write B(NS-1), full drain
    STAGEA1(a1, (NS - 1) * BK);
    #pragma unroll
    for (int h = 0; h < 2; ++h) {
      bf16x8 af[4], gf[4], uf[4];
      const int hoff = h * 512 + loff;
      #pragma unroll
      for (int m = 0; m < 4; ++m) af[m] = *(const bf16x8*)(a0 + (wm * 4 + m) * 1024 + hoff);
      #pragma unroll
      for (int n = 0; n < 4; ++n) {
        gf[n] = *(const bf16x8*)(bg0 + (wn * 4 + n) * 1024 + hoff);
        uf[n] = *(const bf16x8*)(bu0 + (wn * 4 + n) * 1024 + hoff);
      }
      MFMAH1;
      __builtin_amdgcn_sched_barrier(0);
    }
    WRITEB1(bg1, bu1);
    SYNCV(0);
    { ushort* t_;
      t_ = a0; a0 = a1; a1 = t_;
      t_ = bg0; bg0 = bg1; bg1 = t_;
      t_ = bu0; bu0 = bu1; bu1 = t_; }
  }
  {   // step NS-1: compute only
    #pragma unroll
    for (int h = 0; h < 2; ++h) {
      bf16x8 af[4], gf[4], uf[4];
      const int hoff = h * 512 + loff;
      #pragma unroll
      for (int m = 0; m < 4; ++m) af[m] = *(const bf16x8*)(a0 + (wm * 4 + m) * 1024 + hoff);
      #pragma unroll
      for (int n = 0; n < 4; ++n) {
        gf[n] = *(const bf16x8*)(bg0 + (wn * 4 + n) * 1024 + hoff);
        uf[n] = *(const bf16x8*)(bu0 + (wn * 4 + n) * 1024 + hoff);
      }
      MFMAH1;
      __builtin_amdgcn_sched_barrier(0);
    }
  }

  const int prbase = wm * 64 + ((lane >> 4) << 2);
  const int cbase = col0 + wn * 64 + (lane & 15);
  #pragma unroll
  for (int m = 0; m < 4; ++m)
    #pragma unroll
    for (int n = 0; n < 4; ++n)
      #pragma unroll
      for (int j2 = 0; j2 < 4; ++j2) {
        const int pr = prbase + m * 16 + j2;
        const size_t ar = (wm < 2) ? (size_t)(r0a + pr) : (size_t)(r0b + pr - 128);
        float g = accg[m][n][j2];
        float u = accu[m][n][j2];
        float sv = g / (1.f + __expf(-g)) * u;   // silu(g)*u
        actall[ar * IDIM + cbase + n * 16] = f2bf(sv);
      }
}

// ---------------- GEMM2: out = act * Wd^T; shared->d_out, routed->bufr ---
#define LOADB2(k0) { \
  const float4* bp_ = (const float4*)(bptr + (k0)); \
  br[0]=bp_[0]; br[1]=bp_[1]; br[2]=bp_[2]; br[3]=bp_[3]; }

#define WRITEB2(BS) { \
  *(uint4*)((BS) + woff0) = cvt8(br[0], br[1]); \
  *(uint4*)((BS) + woff0 + 128) = cvt8(br[2], br[3]); }

#define MFMAH2 \
  _Pragma("unroll") \
  for (int m = 0; m < 4; ++m) { \
    _Pragma("unroll") \
    for (int n = 0; n < 4; ++n) \
      acc[m][n] = __builtin_amdgcn_mfma_f32_16x16x32_bf16(af[m], bfr[n], acc[m][n], 0, 0, 0); }

__global__ __launch_bounds__(512, 1) void gemm2_kernel(
    const ushort* __restrict__ actall,
    const float* __restrict__ w_down, const float* __restrict__ ws_down,
    const int4* __restrict__ pairs, const int* __restrict__ row2tok,
    float* __restrict__ out, float* __restrict__ bufr)
{
  __shared__ __align__(16) ushort As[2][16384];
  __shared__ __align__(16) ushort Bs_[2][8192];

  // XCD j (= b%8) owns col-panel j for all pairs.
  const int b0 = blockIdx.x;
  const int panel = b0 & 7;
  const int4 td = pairs[b0 >> 3];
  if (td.w == 0) return;
  const int r0a = td.x, r0b = td.y, e = td.z;
  const float* __restrict__ bbase = (e < 0) ? ws_down : w_down + (size_t)e * HDIM * IDIM;
  const int col0 = panel * 128;

  const int tid = threadIdx.x;
  const int lane = tid & 63;
  const int w = tid >> 6;
  const int wm = w >> 1, wn = w & 1;

  const int brow = tid >> 2, bc = tid & 3;
  const float* bptr = bbase + (size_t)(col0 + brow) * IDIM + bc * 16;
  const int woff0 = ((brow >> 4) << 10) + (bc * 2) * 128 + ((brow & 15) << 3);

  const int rowb = (w < 4) ? (r0a + w * 32) : (r0b + (w - 4) * 32);
  const ushort* asrc = actall + (size_t)(rowb + (lane & 15)) * IDIM + (lane >> 4) * 8;
  const int alds0 = w * 2048 + lane * 8;

  ushort* a0 = &As[0][0];
  ushort* a1 = &As[1][0];
  ushort* bs0 = &Bs_[0][0]; ushort* bs1 = &Bs_[1][0];

  float4 br[4];
  const int loff = ((lane >> 4) << 7) + ((lane & 15) << 3);
  f32x4 acc[4][4] = {};

  #define STAGEA2(DST, k0) { \
    gld16((DST) + alds0,        asrc + (k0)); \
    gld16((DST) + alds0 + 512,  asrc + 32 + (k0)); \
    gld16((DST) + alds0 + 1024, asrc + (size_t)16 * IDIM + (k0)); \
    gld16((DST) + alds0 + 1536, asrc + (size_t)16 * IDIM + 32 + (k0)); }

  LOADB2(0);
  STAGEA2(a0, 0);
  WRITEB2(bs0);
  LOADB2(BK);
  SYNCV(4);

  const int NS = IDIM / BK;  // 64
  for (int s = 0; s < NS - 2; ++s) {
    STAGEA2(a1, (s + 1) * BK);
    #pragma unroll
    for (int h = 0; h < 2; ++h) {
      bf16x8 af[4], bfr[4];
      const int hoff = h * 512 + loff;
      #pragma unroll
      for (int m = 0; m < 4; ++m) af[m] = *(const bf16x8*)(a0 + (wm * 4 + m) * 1024 + hoff);
      #pragma unroll
      for (int n = 0; n < 4; ++n) bfr[n] = *(const bf16x8*)(bs0 + (wn * 4 + n) * 1024 + hoff);
      MFMAH2;
      __builtin_amdgcn_sched_barrier(0);
    }
    WRITEB2(bs1);
    LOADB2((s + 2) * BK);
    SYNCV(4);
    { ushort* t_;
      t_ = a0; a0 = a1; a1 = t_;
      t_ = bs0; bs0 = bs1; bs1 = t_; }
  }
  {   // step NS-2
    STAGEA2(a1, (NS - 1) * BK);
    #pragma unroll
    for (int h = 0; h < 2; ++h) {
      bf16x8 af[4], bfr[4];
      const int hoff = h * 512 + loff;
      #pragma unroll
      for (int m = 0; m < 4; ++m) af[m] = *(const bf16x8*)(a0 + (wm * 4 + m) * 1024 + hoff);
      #pragma unroll
      for (int n = 0; n < 4; ++n) bfr[n] = *(const bf16x8*)(bs0 + (wn * 4 + n) * 1024 + hoff);
      MFMAH2;
      __builtin_amdgcn_sched_barrier(0);
    }
    WRITEB2(bs1);
    SYNCV(0);
    { ushort* t_;
      t_ = a0; a0 = a1; a1 = t_;
      t_ = bs0; bs0 = bs1; bs1 = t_; }
  }
  {   // step NS-1
    #pragma unroll
    for (int h = 0; h < 2; ++h) {
      bf16x8 af[4], bfr[4];
      const int hoff = h * 512 + loff;
      #pragma unroll
      for (int m = 0; m < 4; ++m) af[m] = *(const bf16x8*)(a0 + (wm * 4 + m) * 1024 + hoff);
      #pragma unroll
      for (int n = 0; n < 4; ++n) bfr[n] = *(const bf16x8*)(bs0 + (wn * 4 + n) * 1024 + hoff);
      MFMAH2;
      __builtin_amdgcn_sched_barrier(0);
    }
  }

  const int prbase = wm * 64 + ((lane >> 4) << 2);
  const int cbase = col0 + wn * 64 + (lane & 15);
  #pragma unroll
  for (int m = 0; m < 4; ++m)
    #pragma unroll
    for (int j2 = 0; j2 < 4; ++j2) {
      const int pr = prbase + m * 16 + j2;
      const int ar = (wm < 2) ? (r0a + pr) : (r0b + pr - 128);
      if (e < 0) {
        #pragma unroll
        for (int n = 0; n < 4; ++n)
          out[(size_t)ar * HDIM + cbase + n * 16] = acc[m][n][j2];
      } else {
        const int t = row2tok[ar - T_TOK];
        if (t >= 0) {
          #pragma unroll
          for (int n = 0; n < 4; ++n)
            bufr[(size_t)t * HDIM + cbase + n * 16] = acc[m][n][j2];
        }
      }
    }
}

// ---------------- final: out += routed ------------------------------------
__global__ __launch_bounds__(256) void add_kernel(
    float* __restrict__ out, const float* __restrict__ bufr)
{
  const size_t i = ((size_t)blockIdx.x * 256 + threadIdx.x) * 4;
  float4 a = *(float4*)(out + i);
  const float4 b = *(const float4*)(bufr + i);
  a.x += b.x; a.y += b.y; a.z += b.z; a.w += b.w;
  *(float4*)(out + i) = a;
}

extern "C" void kernel_launch(void* const* d_in, const int* in_sizes, int n_in,
                              void* d_out, int out_size, void* d_ws, size_t ws_size,
                              hipStream_t stream)
{
  const float* hs      = (const float*)d_in[0];
  const float* rw      = (const float*)d_in[1];
  const float* w_gate  = (const float*)d_in[2];
  const float* w_up    = (const float*)d_in[3];
  const float* w_down  = (const float*)d_in[4];
  const float* ws_gate = (const float*)d_in[5];
  const float* ws_up   = (const float*)d_in[6];
  const float* ws_down = (const float*)d_in[7];

  float* out = (float*)d_out;
  float* scores_out = out + (size_t)T_TOK * HDIM;

  char* ws = (char*)d_ws;
  ushort* Xall   = (ushort*)ws;                       // 5248*1024*2 = 10747904
  ushort* actall = (ushort*)(ws + 10747904);          // 5248*4096*2 = 42991616
  float*  bufr   = (float*)(ws + 53739520);           // 8388608
  int*    eidx   = (int*)(ws + 62128128);             // 8192
  float*  sval   = (float*)(ws + 62136320);           // 8192
  int*    r2t    = (int*)(ws + 62144512);             // 12800
  int4*   pairs  = (int4*)(ws + 62157312);            // 384

  router_kernel<<<T_TOK / 4, 256, 0, stream>>>(hs, rw, Xall, scores_out, eidx, sval);
  plan_kernel<<<1, 256, 0, stream>>>(eidx, r2t, pairs);
  gather_kernel<<<RROWS, 256, 0, stream>>>(hs, r2t, sval, Xall);
  gemm1_kernel<<<(IDIM / 128) * NP2, 512, 0, stream>>>(
      Xall, w_gate, w_up, ws_gate, ws_up, pairs, actall);
  gemm2_kernel<<<(HDIM / 128) * NP2, 512, 0, stream>>>(
      actall, w_down, ws_down, pairs, r2t, out, bufr);
  add_kernel<<<(T_TOK * HDIM) / 1024, 256, 0, stream>>>(out, bufr);
}